// Round 7
// baseline (363.971 us; speedup 1.0000x reference)
//
#include <hip/hip_runtime.h>
#include <hip/hip_bf16.h>

typedef __bf16 bf16_t;
typedef __bf16 bf16x8 __attribute__((ext_vector_type(8)));
typedef __bf16 bf16x4 __attribute__((ext_vector_type(4)));
typedef float f32x4 __attribute__((ext_vector_type(4)));
typedef unsigned int u32;
typedef const __attribute__((address_space(1))) u32* gptr_t;
typedef __attribute__((address_space(3))) u32* lptr_t;

static constexpr int Bb = 16, Ss = 1024, Hh = 768;

// ---- per-batch mask compaction: tok[b][j] = j-th valid s, cnt[b] = count ----
__global__ __launch_bounds__(256) void compact_mask(
    const int* __restrict__ mask, int* __restrict__ tok, int* __restrict__ cnt)
{
    const int b = blockIdx.x;
    const int t = threadIdx.x;
    const int4 m4 = *(const int4*)&mask[(b << 10) + (t << 2)];
    const int c = (m4.x != 0) + (m4.y != 0) + (m4.z != 0) + (m4.w != 0);
    __shared__ int sb[256];
    sb[t] = c;
    __syncthreads();
    for (int off = 1; off < 256; off <<= 1) {
        int v = (t >= off) ? sb[t - off] : 0;
        __syncthreads();
        sb[t] += v;
        __syncthreads();
    }
    int p = sb[t] - c;  // exclusive prefix
    int* tb = tok + (b << 10);
    if (m4.x) tb[p++] = (t << 2) + 0;
    if (m4.y) tb[p++] = (t << 2) + 1;
    if (m4.z) tb[p++] = (t << 2) + 2;
    if (m4.w) tb[p++] = (t << 2) + 3;
    if (t == 255) cnt[b] = sb[255];
}

// ---- conversions + cvec: weights -> bf16 slab, bias pack, x gather-convert,
// ---- and cvec = W2·relu(b1)+b2 (coalesced block-parallel reduction) ----
__global__ __launch_bounds__(256) void cvt_all(
    const float* __restrict__ x,
    const float* __restrict__ w0, const float* __restrict__ w1,
    const float* __restrict__ w2, const float* __restrict__ w3,
    const float* __restrict__ w4,
    const float* __restrict__ bq, const float* __restrict__ bk,
    const float* __restrict__ bv,
    const float* __restrict__ b1, const float* __restrict__ b2,
    const int* __restrict__ tok, const int* __restrict__ cnt,
    bf16_t* __restrict__ xc, bf16_t* __restrict__ wdst, float* __restrict__ bdst,
    float* __restrict__ cvec)
{
    const int bx = blockIdx.x;
    const int t = threadIdx.x;
    if (bx < 2880) {
        int seg = bx / 576;
        const float* src = seg == 0 ? w0 : seg == 1 ? w1 : seg == 2 ? w2 : seg == 3 ? w3 : w4;
        int i = (bx % 576) * 256 + t;
        float4 v = ((const float4*)src)[i];
        bf16x4 o = { (bf16_t)v.x, (bf16_t)v.y, (bf16_t)v.z, (bf16_t)v.w };
        ((bf16x4*)(wdst + (long)seg * 589824))[i] = o;
    } else if (bx < 2889) {
        int i = (bx - 2880) * 256 + t;
        if (i < 2304)
            bdst[i] = i < 768 ? bq[i] : i < 1536 ? bk[i - 768] : bv[i - 1536];
    } else if (bx < 19273) {
        const int idx = bx - 2889;
        const int b = idx >> 10, j = idx & 1023;
        if (j < cnt[b] && t < 192) {
            const int s = tok[(b << 10) + j];
            float4 v = ((const float4*)(x + ((long)((b << 10) + s)) * 768))[t];
            bf16x4 o = { (bf16_t)v.x, (bf16_t)v.y, (bf16_t)v.z, (bf16_t)v.w };
            ((bf16x4*)(xc + ((long)((b << 10) + j)) * 768))[t] = o;
        }
    } else {
        // cvec: 96 blocks x 8 outputs; 32 lanes reduce one W2 row (coalesced)
        const int o = ((bx - 19273) << 3) + (t >> 5);
        const int l = t & 31;
        const float* wr = w4 + (long)o * 768;
        float acc = 0.f;
        for (int h = l; h < 768; h += 32) acc += wr[h] * fmaxf(b1[h], 0.f);
#pragma unroll
        for (int off = 16; off; off >>= 1) acc += __shfl_down(acc, off, 32);
        if (l == 0) cvec[o] = acc + b2[o];
    }
}

// ---------------- async global->LDS 16B ----------------
__device__ __forceinline__ void async_cp16(const void* g, void* l)
{
    __builtin_amdgcn_global_load_lds((gptr_t)g, (lptr_t)l, 16, 0, 0);
}

enum { EG_QKV = 0, EG_SCORE_C = 1, EG_PV = 2, EG_FFN1 = 3, EG_FFN2 = 4 };

#define SBAR __builtin_amdgcn_s_barrier()
#define VMW(n) asm volatile("s_waitcnt vmcnt(" #n ")" ::: "memory")

// C = epi(A * B^T); 128x128 tile, BK=32, 8 waves (512 thr), per-wave 32x64
// (wm=wid&3 M-quadrant, wn=wid>>2 N-half), MI=2 NI=4.
// *** A operand: DIRECT global->VGPR fragments *** — the MFMA A-frag is
// A[base+(lane&15)][k0+(lane>>4)*8], one 16B load per fragment (canonical
// layout; the old stage-XOR/read-XOR pair cancelled to exactly this).
// 1-iter read-ahead into two STATIC register sets (parity-unrolled loop —
// no dynamic reg indexing). A latency is register-dep waited, not
// barrier-drained; A panels are L2/L3-resident.
// B operand: glds-staged LDS ring-2 (16 KB total), XOR-swizzled as before;
// VMW(0)+s_barrier per iter (B(t+1) issued at top of iter t).
// T1 XCD-chunked swizzle (all grids %8==0). Operands compacted per batch;
// m-tiles (score: also n-tiles) early-exit; PV K = ceil32(cnt).
template <int EPI, int BM, int BN>
__global__ __launch_bounds__(512) void mfma_gemm(
    const bf16_t* __restrict__ A, const bf16_t* __restrict__ B,
    const float* __restrict__ bias, const bf16_t* __restrict__ resid,
    const int* __restrict__ tok, const int* __restrict__ cnt,
    void* __restrict__ Cout, bf16_t* __restrict__ out2, bf16_t* __restrict__ out3,
    int K, int lda, int ldb, long sA, long sB, float scale)
{
    // ---- XCD-chunked bijective swizzle (nwg % 8 == 0 for all our grids) ----
    const int gx = gridDim.x, gy = gridDim.y;
    const int nwg = gx * gy * gridDim.z;
    int lid = blockIdx.x + gx * (blockIdx.y + gy * blockIdx.z);
    lid = (lid & 7) * (nwg >> 3) + (lid >> 3);
    const int bxs = lid % gx;
    const int tmp = lid / gx;
    const int bys = tmp % gy;
    const int bz  = tmp / gy;

    const int cb = cnt[bz];
    const int m0 = bys * BM;
    const int n0 = bxs * BN;
    if (m0 >= cb) return;
    if constexpr (EPI == EG_SCORE_C) { if (n0 >= cb) return; }
    const int Kend = (EPI == EG_PV) ? ((cb + 31) & ~31) : K;
    const int nk = Kend >> 5;  // >= 1

    constexpr int MI = 2, NI = 4;     // per-wave 32x64 of the 128x128 tile
    constexpr int BSZ = BN * 32;      // B elements per buffer

    __shared__ __align__(16) bf16_t Bsl[2 * BSZ];   // ring-2, B only

    const int tid = threadIdx.x;
    const int wid = tid >> 6;     // 0..7
    const int lane = tid & 63;
    const int wm = wid & 3, wn = wid >> 2;

    const bf16_t* Ab = A + (long)bz * sA;
    const bf16_t* Bp = B + (long)bz * sB;

    // B staging: wave w covers rows w*16+(l>>2) (8 waves -> 128 rows);
    // global col chunk XOR-preswizzled (source/read same XOR, rule 21)
    const int srow = (wid << 4) + (lane >> 2);
    const int scol = ((lane & 3) ^ ((lane >> 3) & 3)) << 3;
    const bf16_t* pb0 = Bp + (long)(n0 + srow) * ldb + scol;
    const int woff = wid << 9;  // wave's 16-row staging base within a buffer

    // B fragment read: row=lane&15, kchunk=(lane>>4)^((lane>>1)&3) (2-way free)
    const int frag_off = ((lane & 15) << 5) + (((lane >> 4) ^ ((lane >> 1) & 3)) << 3);

    // A fragments: canonical direct-global addresses
    const int arow = lane & 15;
    const int akc = (lane >> 4) << 3;   // element offset within K-chunk
    const bf16_t* pA0 = Ab + (long)(m0 + wm * 32 + arow) * lda + akc;
    const bf16_t* pA1 = Ab + (long)(m0 + wm * 32 + 16 + arow) * lda + akc;

    f32x4 acc[MI][NI] = {};
    bf16x8 aA[MI], aB[MI], bfr[NI];

    auto prefA = [&](int t, bf16x8* dst) {
        dst[0] = *(const bf16x8*)(pA0 + ((long)t << 5));
        dst[1] = *(const bf16x8*)(pA1 + ((long)t << 5));
    };
    auto stageB = [&](int t, int buf) {
        async_cp16(pb0 + (t << 5), &Bsl[buf * BSZ + woff]);
    };
    auto readB = [&](int buf) {
#pragma unroll
        for (int j = 0; j < NI; j++)
            bfr[j] = *(const bf16x8*)&Bsl[buf * BSZ + ((wn * NI + j) << 9) + frag_off];
    };
    auto mfma8 = [&](const bf16x8* av) {
#pragma unroll
        for (int i = 0; i < MI; i++)
#pragma unroll
            for (int j = 0; j < NI; j++)
                acc[i][j] = __builtin_amdgcn_mfma_f32_16x16x32_bf16(av[i], bfr[j], acc[i][j], 0, 0, 0);
    };

    // prologue: A(0) -> set A regs; B(0) -> buf0
    prefA(0, aA);
    stageB(0, 0);
    __builtin_amdgcn_sched_barrier(0);
    VMW(0); SBAR;

    const int nkE = nk & ~1;
    for (int it = 0; it < nkE; it += 2) {
        // even iter it: compute from setA + buf0; prefetch it+1 into setB/buf1
        prefA(it + 1, aB);
        stageB(it + 1, 1);
        readB(0);
        __builtin_amdgcn_sched_barrier(0);
        mfma8(aA);
        __builtin_amdgcn_sched_barrier(0);
        VMW(0); SBAR;

        // odd iter it+1: compute from setB + buf1; prefetch it+2 into setA/buf0
        const bool m2 = (it + 2) < nk;
        if (m2) { prefA(it + 2, aA); stageB(it + 2, 0); }
        readB(1);
        __builtin_amdgcn_sched_barrier(0);
        mfma8(aB);
        if (m2) { __builtin_amdgcn_sched_barrier(0); VMW(0); SBAR; }
    }
    if (nk & 1) {   // last iter (even index): setA + buf0
        readB(0);
        __builtin_amdgcn_sched_barrier(0);
        mfma8(aA);
    }

    // epilogue — C/D per 16x16 tile: col = lane&15, row = (lane>>4)*4 + reg
    const int mb_ = m0 + wm * 32;
    const int nb_ = n0 + wn * 64;
    const int colw = lane & 15;
    const int rowq = (lane >> 4) << 2;

    if constexpr (EPI == EG_QKV) {
        float bj[NI];
#pragma unroll
        for (int j = 0; j < NI; j++) bj[j] = bias[nb_ + (j << 4) + colw];
        if (nb_ < 1536) {
            bf16_t* C = ((nb_ < 768) ? (bf16_t*)Cout : out2) + (long)bz * 786432;
            const int cbase = (nb_ < 768) ? nb_ : nb_ - 768;
#pragma unroll
            for (int i = 0; i < MI; i++)
#pragma unroll
                for (int j = 0; j < NI; j++)
#pragma unroll
                    for (int r = 0; r < 4; r++) {
                        int row = mb_ + (i << 4) + rowq + r;
                        int col = cbase + (j << 4) + colw;
                        C[(long)row * Hh + col] = (bf16_t)fmaxf(acc[i][j][r] + bj[j], 0.f);
                    }
        } else {
            bf16_t* C = out3 + (long)bz * 786432;  // vTc[b][h][jc]
#pragma unroll
            for (int i = 0; i < MI; i++) {
                const int jc0 = mb_ + (i << 4) + rowq;
#pragma unroll
                for (int j = 0; j < NI; j++) {
                    const int col = nb_ - 1536 + (j << 4) + colw;
                    bf16x4 o = { (bf16_t)(acc[i][j][0] + bj[j]), (bf16_t)(acc[i][j][1] + bj[j]),
                                 (bf16_t)(acc[i][j][2] + bj[j]), (bf16_t)(acc[i][j][3] + bj[j]) };
                    *(bf16x4*)&C[(long)col * 1024 + jc0] = o;
                }
            }
        }
    } else if constexpr (EPI == EG_SCORE_C) {
        // computed T = k·q^T (rows=keys); store S = T^T, no mask (all tokens valid)
        bf16_t* C = (bf16_t*)Cout + (long)bz * 1048576;
#pragma unroll
        for (int i = 0; i < MI; i++) {
            const int kbase = mb_ + (i << 4) + rowq;
#pragma unroll
            for (int j = 0; j < NI; j++) {
                const int qrow = nb_ + (j << 4) + colw;
                bf16x4 o = { (bf16_t)(acc[i][j][0] * scale), (bf16_t)(acc[i][j][1] * scale),
                             (bf16_t)(acc[i][j][2] * scale), (bf16_t)(acc[i][j][3] * scale) };
                *(bf16x4*)&C[(long)qrow * 1024 + kbase] = o;
            }
        }
    } else if constexpr (EPI == EG_FFN2) {
        float* outp = (float*)Cout;
        const bf16_t* crow = resid + (long)bz * 786432;
        const int* tb = tok + (bz << 10);
        float bj[NI];
#pragma unroll
        for (int j = 0; j < NI; j++) bj[j] = bias[nb_ + (j << 4) + colw];
#pragma unroll
        for (int i = 0; i < MI; i++)
#pragma unroll
            for (int r = 0; r < 4; r++) {
                const int jq = mb_ + (i << 4) + rowq + r;
                if (jq < cb) {
                    const int s = tb[jq];
                    float* orow = outp + ((long)((bz << 10) + s)) * 768;
                    const bf16_t* cr = crow + (long)jq * 768;
#pragma unroll
                    for (int j = 0; j < NI; j++) {
                        const int col = nb_ + (j << 4) + colw;
                        orow[col] = acc[i][j][r] + bj[j] + (float)cr[col];
                    }
                }
            }
    } else {
        // EG_PV (plain bf16) / EG_FFN1 (relu+bias bf16), compact per-batch
        bf16_t* C = (bf16_t*)Cout + (long)bz * 786432;
        float bj[NI];
#pragma unroll
        for (int j = 0; j < NI; j++) bj[j] = 0.f;
        if constexpr (EPI == EG_FFN1) {
#pragma unroll
            for (int j = 0; j < NI; j++) bj[j] = bias[nb_ + (j << 4) + colw];
        }
#pragma unroll
        for (int i = 0; i < MI; i++)
#pragma unroll
            for (int j = 0; j < NI; j++)
#pragma unroll
                for (int r = 0; r < 4; r++) {
                    int row = mb_ + (i << 4) + rowq + r;
                    int col = nb_ + (j << 4) + colw;
                    float v = acc[i][j][r] + bj[j];
                    if constexpr (EPI == EG_FFN1) v = fmaxf(v, 0.f);
                    C[(long)row * Hh + col] = (bf16_t)v;
                }
    }
}

// ---- z=0: softmax over compact keys (validity = col < cnt, no mask loads)
// ---- z=1: fill masked output rows with cvec (disjoint from FFN2's rows)
__global__ __launch_bounds__(256) void softmax_rows(
    bf16_t* __restrict__ S_, const int* __restrict__ cnt,
    const int* __restrict__ mask, const float* __restrict__ cvec,
    float* __restrict__ out)
{
    const int b = blockIdx.y;
    const int t = threadIdx.x;

    if (blockIdx.z == 1) {
        const int s = blockIdx.x;
        if (t >= 192 || mask[(b << 10) + s]) return;
        float4 v = ((const float4*)cvec)[t];
        ((float4*)(out + ((long)((b << 10) + s)) * 768))[t] = v;
        return;
    }

    const int jq = blockIdx.x;
    const int cb = cnt[b];
    if (jq >= cb) return;
    bf16_t* p = S_ + (((long)(b << 10)) + jq) * 1024;
    const int t0 = t << 2;

    bf16x4 v4 = *(const bf16x4*)&p[t0];
    float v0 = (t0 + 0 < cb) ? (float)v4[0] : -1e30f;
    float v1 = (t0 + 1 < cb) ? (float)v4[1] : -1e30f;
    float v2 = (t0 + 2 < cb) ? (float)v4[2] : -1e30f;
    float v3 = (t0 + 3 < cb) ? (float)v4[3] : -1e30f;

    float mx = fmaxf(fmaxf(v0, v1), fmaxf(v2, v3));
#pragma unroll
    for (int off = 32; off; off >>= 1) mx = fmaxf(mx, __shfl_down(mx, off, 64));
    __shared__ float redm[4], reds[4];
    if ((t & 63) == 0) redm[t >> 6] = mx;
    __syncthreads();
    mx = fmaxf(fmaxf(redm[0], redm[1]), fmaxf(redm[2], redm[3]));

    // invalid lanes: exp(-1e30 - mx) underflows to exactly 0
    float e0 = __expf(v0 - mx), e1 = __expf(v1 - mx);
    float e2 = __expf(v2 - mx), e3 = __expf(v3 - mx);
    float sm = e0 + e1 + e2 + e3;
#pragma unroll
    for (int off = 32; off; off >>= 1) sm += __shfl_down(sm, off, 64);
    if ((t & 63) == 0) reds[t >> 6] = sm;
    __syncthreads();
    sm = reds[0] + reds[1] + reds[2] + reds[3];

    const float inv = 1.f / sm;
    bf16x4 o = { (bf16_t)(e0 * inv), (bf16_t)(e1 * inv),
                 (bf16_t)(e2 * inv), (bf16_t)(e3 * inv) };
    *(bf16x4*)&p[t0] = o;
}

extern "C" void kernel_launch(void* const* d_in, const int* in_sizes, int n_in,
                              void* d_out, int out_size, void* d_ws, size_t ws_size,
                              hipStream_t stream)
{
    const float* x  = (const float*)d_in[0];
    const int* mask = (const int*)d_in[1];
    const float* Wq = (const float*)d_in[2];
    const float* bq = (const float*)d_in[3];
    const float* Wk = (const float*)d_in[4];
    const float* bk = (const float*)d_in[5];
    const float* Wv = (const float*)d_in[6];
    const float* bv = (const float*)d_in[7];
    const float* W1 = (const float*)d_in[8];
    const float* b1 = (const float*)d_in[9];
    const float* W2 = (const float*)d_in[10];
    const float* b2 = (const float*)d_in[11];
    float* out = (float*)d_out;

    // workspace layout (~140.2 MB)
    char* w = (char*)d_ws;
    bf16_t* xc   = (bf16_t*)(w + 0);            // [16][1024][768] compact, reused as ctxc
    bf16_t* qc   = (bf16_t*)(w + 25165824);     // reused as h1c
    bf16_t* kc   = (bf16_t*)(w + 50331648);
    bf16_t* vTc  = (bf16_t*)(w + 75497472);     // [16][768][1024] compact cols
    bf16_t* sc   = (bf16_t*)(w + 100663296);    // [16][1024][1024] bf16
    bf16_t* wqkv = (bf16_t*)(w + 134217728);    // [2304,768] = Wq|Wk|Wv
    bf16_t* w1b  = (bf16_t*)(w + 137756672);
    bf16_t* w2b  = (bf16_t*)(w + 138936320);
    float*  bqkv = (float*) (w + 140115968);    // [2304]
    int*    tok  = (int*)   (w + 140125184);    // [16][1024]
    int*    cnt  = (int*)   (w + 140190720);    // [16]
    float*  cvec = (float*) (w + 140190784);    // [768]
    bf16_t* ctxc = xc;
    bf16_t* h1c  = qc;

    const float inv_sqrt_h = 0.036084391824351615f; // 1/sqrt(768)
    dim3 blk(256);
    dim3 blk8(512);

    compact_mask<<<16, blk, 0, stream>>>(mask, tok, cnt);
    cvt_all<<<19369, blk, 0, stream>>>(x, Wq, Wk, Wv, W1, W2, bq, bk, bv, b1, b2,
                                       tok, cnt, xc, wqkv, bqkv, cvec);

    // qc|kc|vTc = epi(xc · [Wq|Wk|Wv]^T + bqkv), compact rows
    mfma_gemm<EG_QKV, 128, 128><<<dim3(18, 8, 16), blk8, 0, stream>>>(
        xc, wqkv, bqkv, nullptr, tok, cnt, qc, kc, vTc,
        768, 768, 768, 786432, 0, 1.f);

    // sc[jq][jk] = (kc·qc^T)^T * scale  (both dims compact)
    mfma_gemm<EG_SCORE_C, 128, 128><<<dim3(8, 8, 16), blk8, 0, stream>>>(
        kc, qc, nullptr, nullptr, tok, cnt, sc, nullptr, nullptr,
        768, 768, 768, 786432, 786432, inv_sqrt_h);

    // z=0: softmax over valid keys in place; z=1: masked out rows = cvec
    softmax_rows<<<dim3(1024, 16, 2), blk, 0, stream>>>(sc, cnt, mask, cvec, out);

    // ctxc = sc · vTc^T   (K = ceil32(cnt) per batch)
    mfma_gemm<EG_PV, 128, 128><<<dim3(6, 8, 16), blk8, 0, stream>>>(
        sc, vTc, nullptr, nullptr, tok, cnt, ctxc, nullptr, nullptr,
        0, 1024, 1024, 1048576, 786432, 1.f);

    // h1c = relu(ctxc · W1^T + b1)
    mfma_gemm<EG_FFN1, 128, 128><<<dim3(6, 8, 16), blk8, 0, stream>>>(
        ctxc, w1b, b1, nullptr, tok, cnt, h1c, nullptr, nullptr,
        768, 768, 768, 786432, 0, 1.f);

    // out[b][tok[jq]] = h1c · W2^T + b2 + ctxc   (scatter, fp32)
    mfma_gemm<EG_FFN2, 128, 128><<<dim3(6, 8, 16), blk8, 0, stream>>>(
        h1c, w2b, b2, ctxc, tok, cnt, out, nullptr, nullptr,
        768, 768, 768, 786432, 0, 1.f);
}

// Round 8
// 273.839 us; speedup vs baseline: 1.3291x; 1.3291x over previous
//
#include <hip/hip_runtime.h>
#include <hip/hip_bf16.h>

typedef __bf16 bf16_t;
typedef __bf16 bf16x8 __attribute__((ext_vector_type(8)));
typedef __bf16 bf16x4 __attribute__((ext_vector_type(4)));
typedef float f32x4 __attribute__((ext_vector_type(4)));
typedef unsigned int u32;
typedef const __attribute__((address_space(1))) u32* gptr_t;
typedef __attribute__((address_space(3))) u32* lptr_t;

static constexpr int Bb = 16, Ss = 1024, Hh = 768;

// ---- per-batch mask compaction: tok[b][j] = j-th valid s, cnt[b] = count ----
__global__ __launch_bounds__(256) void compact_mask(
    const int* __restrict__ mask, int* __restrict__ tok, int* __restrict__ cnt)
{
    const int b = blockIdx.x;
    const int t = threadIdx.x;
    const int4 m4 = *(const int4*)&mask[(b << 10) + (t << 2)];
    const int c = (m4.x != 0) + (m4.y != 0) + (m4.z != 0) + (m4.w != 0);
    __shared__ int sb[256];
    sb[t] = c;
    __syncthreads();
    for (int off = 1; off < 256; off <<= 1) {
        int v = (t >= off) ? sb[t - off] : 0;
        __syncthreads();
        sb[t] += v;
        __syncthreads();
    }
    int p = sb[t] - c;  // exclusive prefix
    int* tb = tok + (b << 10);
    if (m4.x) tb[p++] = (t << 2) + 0;
    if (m4.y) tb[p++] = (t << 2) + 1;
    if (m4.z) tb[p++] = (t << 2) + 2;
    if (m4.w) tb[p++] = (t << 2) + 3;
    if (t == 255) cnt[b] = sb[255];
}

// ---- conversions + cvec: weights -> bf16 slab, bias pack, x gather-convert,
// ---- and cvec = W2·relu(b1)+b2 (coalesced block-parallel reduction) ----
__global__ __launch_bounds__(256) void cvt_all(
    const float* __restrict__ x,
    const float* __restrict__ w0, const float* __restrict__ w1,
    const float* __restrict__ w2, const float* __restrict__ w3,
    const float* __restrict__ w4,
    const float* __restrict__ bq, const float* __restrict__ bk,
    const float* __restrict__ bv,
    const float* __restrict__ b1, const float* __restrict__ b2,
    const int* __restrict__ tok, const int* __restrict__ cnt,
    bf16_t* __restrict__ xc, bf16_t* __restrict__ wdst, float* __restrict__ bdst,
    float* __restrict__ cvec)
{
    const int bx = blockIdx.x;
    const int t = threadIdx.x;
    if (bx < 2880) {
        int seg = bx / 576;
        const float* src = seg == 0 ? w0 : seg == 1 ? w1 : seg == 2 ? w2 : seg == 3 ? w3 : w4;
        int i = (bx % 576) * 256 + t;
        float4 v = ((const float4*)src)[i];
        bf16x4 o = { (bf16_t)v.x, (bf16_t)v.y, (bf16_t)v.z, (bf16_t)v.w };
        ((bf16x4*)(wdst + (long)seg * 589824))[i] = o;
    } else if (bx < 2889) {
        int i = (bx - 2880) * 256 + t;
        if (i < 2304)
            bdst[i] = i < 768 ? bq[i] : i < 1536 ? bk[i - 768] : bv[i - 1536];
    } else if (bx < 19273) {
        const int idx = bx - 2889;
        const int b = idx >> 10, j = idx & 1023;
        if (j < cnt[b] && t < 192) {
            const int s = tok[(b << 10) + j];
            float4 v = ((const float4*)(x + ((long)((b << 10) + s)) * 768))[t];
            bf16x4 o = { (bf16_t)v.x, (bf16_t)v.y, (bf16_t)v.z, (bf16_t)v.w };
            ((bf16x4*)(xc + ((long)((b << 10) + j)) * 768))[t] = o;
        }
    } else {
        // cvec: 96 blocks x 8 outputs; 32 lanes reduce one W2 row (coalesced)
        const int o = ((bx - 19273) << 3) + (t >> 5);
        const int l = t & 31;
        const float* wr = w4 + (long)o * 768;
        float acc = 0.f;
        for (int h = l; h < 768; h += 32) acc += wr[h] * fmaxf(b1[h], 0.f);
#pragma unroll
        for (int off = 16; off; off >>= 1) acc += __shfl_down(acc, off, 32);
        if (l == 0) cvec[o] = acc + b2[o];
    }
}

// ---------------- async global->LDS 16B ----------------
__device__ __forceinline__ void async_cp16(const void* g, void* l)
{
    __builtin_amdgcn_global_load_lds((gptr_t)g, (lptr_t)l, 16, 0, 0);
}

enum { EG_QKV = 0, EG_SCORE_C = 1, EG_PV = 2, EG_FFN1 = 3, EG_FFN2 = 4 };

#define SBAR __builtin_amdgcn_s_barrier()
#define VMW(n) asm volatile("s_waitcnt vmcnt(" #n ")" ::: "memory")

// C = epi(A * B^T); 128x128 tile, *** BK=64 *** (half the K-iterations: the
// measured per-iteration time is a ~constant latency quantum across all
// schedules tried, so time ~ iteration count), 8 waves (512 thr), per-wave
// 32x64 (wm=wid&3, wn=wid>>2), MI=2 NI=4, 16 MFMA : 12 ds_read per wave-iter.
// Ring-2 LDS (2 x 32KB = 64KB, 2 blocks/CU). stage(t+1) issued at top of
// iter t (one long compute phase of slack); VMW(0)+s_barrier per iter.
// LDS [128 rows][64 cols] per tile; 16B-chunk XOR swizzle chunk^=(row&7)
// (row stride 128B would be 32-way bank conflict; XOR spreads 8 rows over
// 8 chunk slots -> 2-way, free). Staging pre-swizzles the GLOBAL source
// column (rule 21: glds dest stays linear), read applies the same XOR.
// T1 XCD-chunked swizzle (all grids %8==0). Operands compacted per batch;
// m-tiles (score: also n-tiles) early-exit; PV K = ceil64(cnt).
template <int EPI, int BM, int BN>
__global__ __launch_bounds__(512) void mfma_gemm(
    const bf16_t* __restrict__ A, const bf16_t* __restrict__ B,
    const float* __restrict__ bias, const bf16_t* __restrict__ resid,
    const int* __restrict__ tok, const int* __restrict__ cnt,
    void* __restrict__ Cout, bf16_t* __restrict__ out2, bf16_t* __restrict__ out3,
    int K, int lda, int ldb, long sA, long sB, float scale)
{
    // ---- XCD-chunked bijective swizzle (nwg % 8 == 0 for all our grids) ----
    const int gx = gridDim.x, gy = gridDim.y;
    const int nwg = gx * gy * gridDim.z;
    int lid = blockIdx.x + gx * (blockIdx.y + gy * blockIdx.z);
    lid = (lid & 7) * (nwg >> 3) + (lid >> 3);
    const int bxs = lid % gx;
    const int tmp = lid / gx;
    const int bys = tmp % gy;
    const int bz  = tmp / gy;

    const int cb = cnt[bz];
    const int m0 = bys * BM;
    const int n0 = bxs * BN;
    if (m0 >= cb) return;
    if constexpr (EPI == EG_SCORE_C) { if (n0 >= cb) return; }
    const int Kend = (EPI == EG_PV) ? ((cb + 63) & ~63) : K;
    const int nk = Kend >> 6;  // 64-wide K-tiles, >= 1

    constexpr int MI = 2, NI = 4;       // per-wave 32x64 of the 128x128 tile
    constexpr int TSZ = 128 * 64;       // elements per tile buffer (16 KB)

    __shared__ __align__(16) bf16_t Asl[2 * TSZ];
    __shared__ __align__(16) bf16_t Bsl[2 * TSZ];

    const int tid = threadIdx.x;
    const int wid = tid >> 6;     // 0..7
    const int lane = tid & 63;
    const int wm = wid & 3, wn = wid >> 2;

    const bf16_t* Ab = A + (long)bz * sA;
    const bf16_t* Bp = B + (long)bz * sB;

    // staging: per glds, 64 lanes cover 8 rows x 8 chunks(16B); wave wid
    // stages rows wid*16 + q*8 + (lane>>3), q=0,1, for A and B.
    // GLOBAL column chunk pre-XOR'ed with (lane>>3) = row&7 (rule 21).
    const int srow8 = lane >> 3;
    const int scg = ((lane & 7) ^ srow8) << 3;   // element offset in 64-col window

    const bf16_t* pa[2];
    const bf16_t* pb[2];
#pragma unroll
    for (int q = 0; q < 2; q++) {
        pa[q] = Ab + (long)(m0 + (wid << 4) + (q << 3) + srow8) * lda + scg;
        pb[q] = Bp + (long)(n0 + (wid << 4) + (q << 3) + srow8) * ldb + scg;
    }
    const int wrow = wid << 4;  // wave's first staged row

    // fragment read: row=lane&15; nominal chunk kk*4+(lane>>4) XOR (row&7)
    const int arow = lane & 15;
    const int axr = lane & 7;
    const int f0 = (arow << 6) + (((lane >> 4)      ^ axr) << 3);  // kk=0
    const int f1 = (arow << 6) + ((((lane >> 4) + 4) ^ axr) << 3); // kk=1

    auto stage = [&](int tk, int buf) {
        const long ko = (long)tk << 6;
#pragma unroll
        for (int q = 0; q < 2; q++) {
            async_cp16(pa[q] + ko, &Asl[buf * TSZ + ((wrow + (q << 3)) << 6)]);
            async_cp16(pb[q] + ko, &Bsl[buf * TSZ + ((wrow + (q << 3)) << 6)]);
        }
    };

    f32x4 acc[MI][NI] = {};

    // prologue
    stage(0, 0);
    __builtin_amdgcn_sched_barrier(0);
    VMW(0); SBAR;

    for (int t = 0; t < nk; ++t) {
        if (t + 1 < nk) stage(t + 1, (t + 1) & 1);

        const int cba = (t & 1) * TSZ;
        bf16x8 af[MI][2], bfr[NI][2];
#pragma unroll
        for (int i = 0; i < MI; i++) {
            const int rb = cba + ((wm * MI + i) << 10);   // (wm*32+i*16)*64
            af[i][0] = *(const bf16x8*)&Asl[rb + f0];
            af[i][1] = *(const bf16x8*)&Asl[rb + f1];
        }
#pragma unroll
        for (int j = 0; j < NI; j++) {
            const int rb = cba + ((wn * NI + j) << 10);   // (wn*64+j*16)*64
            bfr[j][0] = *(const bf16x8*)&Bsl[rb + f0];
            bfr[j][1] = *(const bf16x8*)&Bsl[rb + f1];
        }
        __builtin_amdgcn_sched_barrier(0);
#pragma unroll
        for (int kk = 0; kk < 2; kk++)
#pragma unroll
            for (int i = 0; i < MI; i++)
#pragma unroll
                for (int j = 0; j < NI; j++)
                    acc[i][j] = __builtin_amdgcn_mfma_f32_16x16x32_bf16(
                        af[i][kk], bfr[j][kk], acc[i][j], 0, 0, 0);
        __builtin_amdgcn_sched_barrier(0);
        if (t + 1 < nk) { VMW(0); SBAR; }
    }

    // epilogue — C/D per 16x16 tile: col = lane&15, row = (lane>>4)*4 + reg
    const int mb_ = m0 + wm * 32;
    const int nb_ = n0 + wn * 64;
    const int colw = lane & 15;
    const int rowq = (lane >> 4) << 2;

    if constexpr (EPI == EG_QKV) {
        float bj[NI];
#pragma unroll
        for (int j = 0; j < NI; j++) bj[j] = bias[nb_ + (j << 4) + colw];
        if (nb_ < 1536) {
            bf16_t* C = ((nb_ < 768) ? (bf16_t*)Cout : out2) + (long)bz * 786432;
            const int cbase = (nb_ < 768) ? nb_ : nb_ - 768;
#pragma unroll
            for (int i = 0; i < MI; i++)
#pragma unroll
                for (int j = 0; j < NI; j++)
#pragma unroll
                    for (int r = 0; r < 4; r++) {
                        int row = mb_ + (i << 4) + rowq + r;
                        int col = cbase + (j << 4) + colw;
                        C[(long)row * Hh + col] = (bf16_t)fmaxf(acc[i][j][r] + bj[j], 0.f);
                    }
        } else {
            bf16_t* C = out3 + (long)bz * 786432;  // vTc[b][h][jc]
#pragma unroll
            for (int i = 0; i < MI; i++) {
                const int jc0 = mb_ + (i << 4) + rowq;
#pragma unroll
                for (int j = 0; j < NI; j++) {
                    const int col = nb_ - 1536 + (j << 4) + colw;
                    bf16x4 o = { (bf16_t)(acc[i][j][0] + bj[j]), (bf16_t)(acc[i][j][1] + bj[j]),
                                 (bf16_t)(acc[i][j][2] + bj[j]), (bf16_t)(acc[i][j][3] + bj[j]) };
                    *(bf16x4*)&C[(long)col * 1024 + jc0] = o;
                }
            }
        }
    } else if constexpr (EPI == EG_SCORE_C) {
        // computed T = k·q^T (rows=keys); store S = T^T, no mask (all tokens valid)
        bf16_t* C = (bf16_t*)Cout + (long)bz * 1048576;
#pragma unroll
        for (int i = 0; i < MI; i++) {
            const int kbase = mb_ + (i << 4) + rowq;
#pragma unroll
            for (int j = 0; j < NI; j++) {
                const int qrow = nb_ + (j << 4) + colw;
                bf16x4 o = { (bf16_t)(acc[i][j][0] * scale), (bf16_t)(acc[i][j][1] * scale),
                             (bf16_t)(acc[i][j][2] * scale), (bf16_t)(acc[i][j][3] * scale) };
                *(bf16x4*)&C[(long)qrow * 1024 + kbase] = o;
            }
        }
    } else if constexpr (EPI == EG_FFN2) {
        float* outp = (float*)Cout;
        const bf16_t* crow = resid + (long)bz * 786432;
        const int* tb = tok + (bz << 10);
        float bj[NI];
#pragma unroll
        for (int j = 0; j < NI; j++) bj[j] = bias[nb_ + (j << 4) + colw];
#pragma unroll
        for (int i = 0; i < MI; i++)
#pragma unroll
            for (int r = 0; r < 4; r++) {
                const int jq = mb_ + (i << 4) + rowq + r;
                if (jq < cb) {
                    const int s = tb[jq];
                    float* orow = outp + ((long)((bz << 10) + s)) * 768;
                    const bf16_t* cr = crow + (long)jq * 768;
#pragma unroll
                    for (int j = 0; j < NI; j++) {
                        const int col = nb_ + (j << 4) + colw;
                        orow[col] = acc[i][j][r] + bj[j] + (float)cr[col];
                    }
                }
            }
    } else {
        // EG_PV (plain bf16) / EG_FFN1 (relu+bias bf16), compact per-batch
        bf16_t* C = (bf16_t*)Cout + (long)bz * 786432;
        float bj[NI];
#pragma unroll
        for (int j = 0; j < NI; j++) bj[j] = 0.f;
        if constexpr (EPI == EG_FFN1) {
#pragma unroll
            for (int j = 0; j < NI; j++) bj[j] = bias[nb_ + (j << 4) + colw];
        }
#pragma unroll
        for (int i = 0; i < MI; i++)
#pragma unroll
            for (int j = 0; j < NI; j++)
#pragma unroll
                for (int r = 0; r < 4; r++) {
                    int row = mb_ + (i << 4) + rowq + r;
                    int col = nb_ + (j << 4) + colw;
                    float v = acc[i][j][r] + bj[j];
                    if constexpr (EPI == EG_FFN1) v = fmaxf(v, 0.f);
                    C[(long)row * Hh + col] = (bf16_t)v;
                }
    }
}

// ---- z=0: softmax over compact keys (validity = col < cnt, no mask loads)
// ---- z=1: fill masked output rows with cvec (disjoint from FFN2's rows)
__global__ __launch_bounds__(256) void softmax_rows(
    bf16_t* __restrict__ S_, const int* __restrict__ cnt,
    const int* __restrict__ mask, const float* __restrict__ cvec,
    float* __restrict__ out)
{
    const int b = blockIdx.y;
    const int t = threadIdx.x;

    if (blockIdx.z == 1) {
        const int s = blockIdx.x;
        if (t >= 192 || mask[(b << 10) + s]) return;
        float4 v = ((const float4*)cvec)[t];
        ((float4*)(out + ((long)((b << 10) + s)) * 768))[t] = v;
        return;
    }

    const int jq = blockIdx.x;
    const int cb = cnt[b];
    if (jq >= cb) return;
    bf16_t* p = S_ + (((long)(b << 10)) + jq) * 1024;
    const int t0 = t << 2;

    bf16x4 v4 = *(const bf16x4*)&p[t0];
    float v0 = (t0 + 0 < cb) ? (float)v4[0] : -1e30f;
    float v1 = (t0 + 1 < cb) ? (float)v4[1] : -1e30f;
    float v2 = (t0 + 2 < cb) ? (float)v4[2] : -1e30f;
    float v3 = (t0 + 3 < cb) ? (float)v4[3] : -1e30f;

    float mx = fmaxf(fmaxf(v0, v1), fmaxf(v2, v3));
#pragma unroll
    for (int off = 32; off; off >>= 1) mx = fmaxf(mx, __shfl_down(mx, off, 64));
    __shared__ float redm[4], reds[4];
    if ((t & 63) == 0) redm[t >> 6] = mx;
    __syncthreads();
    mx = fmaxf(fmaxf(redm[0], redm[1]), fmaxf(redm[2], redm[3]));

    // invalid lanes: exp(-1e30 - mx) underflows to exactly 0
    float e0 = __expf(v0 - mx), e1 = __expf(v1 - mx);
    float e2 = __expf(v2 - mx), e3 = __expf(v3 - mx);
    float sm = e0 + e1 + e2 + e3;
#pragma unroll
    for (int off = 32; off; off >>= 1) sm += __shfl_down(sm, off, 64);
    if ((t & 63) == 0) reds[t >> 6] = sm;
    __syncthreads();
    sm = reds[0] + reds[1] + reds[2] + reds[3];

    const float inv = 1.f / sm;
    bf16x4 o = { (bf16_t)(e0 * inv), (bf16_t)(e1 * inv),
                 (bf16_t)(e2 * inv), (bf16_t)(e3 * inv) };
    *(bf16x4*)&p[t0] = o;
}

extern "C" void kernel_launch(void* const* d_in, const int* in_sizes, int n_in,
                              void* d_out, int out_size, void* d_ws, size_t ws_size,
                              hipStream_t stream)
{
    const float* x  = (const float*)d_in[0];
    const int* mask = (const int*)d_in[1];
    const float* Wq = (const float*)d_in[2];
    const float* bq = (const float*)d_in[3];
    const float* Wk = (const float*)d_in[4];
    const float* bk = (const float*)d_in[5];
    const float* Wv = (const float*)d_in[6];
    const float* bv = (const float*)d_in[7];
    const float* W1 = (const float*)d_in[8];
    const float* b1 = (const float*)d_in[9];
    const float* W2 = (const float*)d_in[10];
    const float* b2 = (const float*)d_in[11];
    float* out = (float*)d_out;

    // workspace layout (~140.2 MB)
    char* w = (char*)d_ws;
    bf16_t* xc   = (bf16_t*)(w + 0);            // [16][1024][768] compact, reused as ctxc
    bf16_t* qc   = (bf16_t*)(w + 25165824);     // reused as h1c
    bf16_t* kc   = (bf16_t*)(w + 50331648);
    bf16_t* vTc  = (bf16_t*)(w + 75497472);     // [16][768][1024] compact cols
    bf16_t* sc   = (bf16_t*)(w + 100663296);    // [16][1024][1024] bf16
    bf16_t* wqkv = (bf16_t*)(w + 134217728);    // [2304,768] = Wq|Wk|Wv
    bf16_t* w1b  = (bf16_t*)(w + 137756672);
    bf16_t* w2b  = (bf16_t*)(w + 138936320);
    float*  bqkv = (float*) (w + 140115968);    // [2304]
    int*    tok  = (int*)   (w + 140125184);    // [16][1024]
    int*    cnt  = (int*)   (w + 140190720);    // [16]
    float*  cvec = (float*) (w + 140190784);    // [768]
    bf16_t* ctxc = xc;
    bf16_t* h1c  = qc;

    const float inv_sqrt_h = 0.036084391824351615f; // 1/sqrt(768)
    dim3 blk(256);
    dim3 blk8(512);

    compact_mask<<<16, blk, 0, stream>>>(mask, tok, cnt);
    cvt_all<<<19369, blk, 0, stream>>>(x, Wq, Wk, Wv, W1, W2, bq, bk, bv, b1, b2,
                                       tok, cnt, xc, wqkv, bqkv, cvec);

    // qc|kc|vTc = epi(xc · [Wq|Wk|Wv]^T + bqkv), compact rows
    mfma_gemm<EG_QKV, 128, 128><<<dim3(18, 8, 16), blk8, 0, stream>>>(
        xc, wqkv, bqkv, nullptr, tok, cnt, qc, kc, vTc,
        768, 768, 768, 786432, 0, 1.f);

    // sc[jq][jk] = (kc·qc^T)^T * scale  (both dims compact)
    mfma_gemm<EG_SCORE_C, 128, 128><<<dim3(8, 8, 16), blk8, 0, stream>>>(
        kc, qc, nullptr, nullptr, tok, cnt, sc, nullptr, nullptr,
        768, 768, 768, 786432, 786432, inv_sqrt_h);

    // z=0: softmax over valid keys in place; z=1: masked out rows = cvec
    softmax_rows<<<dim3(1024, 16, 2), blk, 0, stream>>>(sc, cnt, mask, cvec, out);

    // ctxc = sc · vTc^T   (K = ceil64(cnt) per batch)
    mfma_gemm<EG_PV, 128, 128><<<dim3(6, 8, 16), blk8, 0, stream>>>(
        sc, vTc, nullptr, nullptr, tok, cnt, ctxc, nullptr, nullptr,
        0, 1024, 1024, 1048576, 786432, 1.f);

    // h1c = relu(ctxc · W1^T + b1)
    mfma_gemm<EG_FFN1, 128, 128><<<dim3(6, 8, 16), blk8, 0, stream>>>(
        ctxc, w1b, b1, nullptr, tok, cnt, h1c, nullptr, nullptr,
        768, 768, 768, 786432, 0, 1.f);

    // out[b][tok[jq]] = h1c · W2^T + b2 + ctxc   (scatter, fp32)
    mfma_gemm<EG_FFN2, 128, 128><<<dim3(6, 8, 16), blk8, 0, stream>>>(
        h1c, w2b, b2, ctxc, tok, cnt, out, nullptr, nullptr,
        768, 768, 768, 786432, 0, 1.f);
}

// Round 9
// 269.530 us; speedup vs baseline: 1.3504x; 1.0160x over previous
//
#include <hip/hip_runtime.h>
#include <hip/hip_bf16.h>

typedef __bf16 bf16_t;
typedef __bf16 bf16x8 __attribute__((ext_vector_type(8)));
typedef __bf16 bf16x4 __attribute__((ext_vector_type(4)));
typedef float f32x4 __attribute__((ext_vector_type(4)));
typedef unsigned int u32;
typedef const __attribute__((address_space(1))) u32* gptr_t;
typedef __attribute__((address_space(3))) u32* lptr_t;

static constexpr int Bb = 16, Ss = 1024, Hh = 768;

// ---- per-batch mask compaction: tok[b][j] = j-th valid s, cnt[b] = count ----
__global__ __launch_bounds__(256) void compact_mask(
    const int* __restrict__ mask, int* __restrict__ tok, int* __restrict__ cnt)
{
    const int b = blockIdx.x;
    const int t = threadIdx.x;
    const int4 m4 = *(const int4*)&mask[(b << 10) + (t << 2)];
    const int c = (m4.x != 0) + (m4.y != 0) + (m4.z != 0) + (m4.w != 0);
    __shared__ int sb[256];
    sb[t] = c;
    __syncthreads();
    for (int off = 1; off < 256; off <<= 1) {
        int v = (t >= off) ? sb[t - off] : 0;
        __syncthreads();
        sb[t] += v;
        __syncthreads();
    }
    int p = sb[t] - c;  // exclusive prefix
    int* tb = tok + (b << 10);
    if (m4.x) tb[p++] = (t << 2) + 0;
    if (m4.y) tb[p++] = (t << 2) + 1;
    if (m4.z) tb[p++] = (t << 2) + 2;
    if (m4.w) tb[p++] = (t << 2) + 3;
    if (t == 255) cnt[b] = sb[255];
}

// ---- conversions + cvec: weights -> bf16 slab, bias pack, x gather-convert,
// ---- and cvec = W2·relu(b1)+b2 (coalesced block-parallel reduction) ----
__global__ __launch_bounds__(256) void cvt_all(
    const float* __restrict__ x,
    const float* __restrict__ w0, const float* __restrict__ w1,
    const float* __restrict__ w2, const float* __restrict__ w3,
    const float* __restrict__ w4,
    const float* __restrict__ bq, const float* __restrict__ bk,
    const float* __restrict__ bv,
    const float* __restrict__ b1, const float* __restrict__ b2,
    const int* __restrict__ tok, const int* __restrict__ cnt,
    bf16_t* __restrict__ xc, bf16_t* __restrict__ wdst, float* __restrict__ bdst,
    float* __restrict__ cvec)
{
    const int bx = blockIdx.x;
    const int t = threadIdx.x;
    if (bx < 2880) {
        int seg = bx / 576;
        const float* src = seg == 0 ? w0 : seg == 1 ? w1 : seg == 2 ? w2 : seg == 3 ? w3 : w4;
        int i = (bx % 576) * 256 + t;
        float4 v = ((const float4*)src)[i];
        bf16x4 o = { (bf16_t)v.x, (bf16_t)v.y, (bf16_t)v.z, (bf16_t)v.w };
        ((bf16x4*)(wdst + (long)seg * 589824))[i] = o;
    } else if (bx < 2889) {
        int i = (bx - 2880) * 256 + t;
        if (i < 2304)
            bdst[i] = i < 768 ? bq[i] : i < 1536 ? bk[i - 768] : bv[i - 1536];
    } else if (bx < 19273) {
        const int idx = bx - 2889;
        const int b = idx >> 10, j = idx & 1023;
        if (j < cnt[b] && t < 192) {
            const int s = tok[(b << 10) + j];
            float4 v = ((const float4*)(x + ((long)((b << 10) + s)) * 768))[t];
            bf16x4 o = { (bf16_t)v.x, (bf16_t)v.y, (bf16_t)v.z, (bf16_t)v.w };
            ((bf16x4*)(xc + ((long)((b << 10) + j)) * 768))[t] = o;
        }
    } else {
        // cvec: 96 blocks x 8 outputs; 32 lanes reduce one W2 row (coalesced)
        const int o = ((bx - 19273) << 3) + (t >> 5);
        const int l = t & 31;
        const float* wr = w4 + (long)o * 768;
        float acc = 0.f;
        for (int h = l; h < 768; h += 32) acc += wr[h] * fmaxf(b1[h], 0.f);
#pragma unroll
        for (int off = 16; off; off >>= 1) acc += __shfl_down(acc, off, 32);
        if (l == 0) cvec[o] = acc + b2[o];
    }
}

// ---------------- async global->LDS 16B ----------------
__device__ __forceinline__ void async_cp16(const void* g, void* l)
{
    __builtin_amdgcn_global_load_lds((gptr_t)g, (lptr_t)l, 16, 0, 0);
}

enum { EG_QKV = 0, EG_SCORE_C = 1, EG_PV = 2, EG_FFN1 = 3, EG_FFN2 = 4 };

#define SBAR __builtin_amdgcn_s_barrier()
#define VMW(n) asm volatile("s_waitcnt vmcnt(" #n ")" ::: "memory")

// C = epi(A * B^T); 128x128 tile, BK=64, 8 waves (512 thr), per-wave 32x64
// (wm=wid&3, wn=wid>>2), MI=2 NI=4. Ring-2 LDS (64KB, 2 blocks/CU);
// stage(t+1) at top of iter t; VMW(0)+s_barrier per iter. LDS [128][64]
// per tile, 16B-chunk XOR swizzle chunk^=(row&7) (source pre-swizzled,
// read same XOR — rule 21).
// *** DISPATCH-DENSE tile mapping ***: instead of a 3D grid with ~50% of
// blocks early-exiting (active blocks scattered over CUs -> straggler CUs
// set the makespan), each block reads cnt[0..15], computes the exact
// active-tile count, and the FIRST tot raw block indices (dispatch-front,
// round-robin over CUs -> even per-CU load) map onto active tiles via the
// runtime-bijective XCD chunk swizzle (m204: q=tot/8, r=tot%8) + a
// per-batch walk (recomputes counts; no runtime-indexed local array).
// Dead blocks form the dispatch TAIL and exit instantly.
// NT = n-tiles per batch (compile-time; score uses am(b) instead).
// PV K = ceil64(cnt).
template <int EPI, int NT>
__global__ __launch_bounds__(512) void mfma_gemm(
    const bf16_t* __restrict__ A, const bf16_t* __restrict__ B,
    const float* __restrict__ bias, const bf16_t* __restrict__ resid,
    const int* __restrict__ tok, const int* __restrict__ cnt,
    void* __restrict__ Cout, bf16_t* __restrict__ out2, bf16_t* __restrict__ out3,
    int K, int lda, int ldb, long sA, long sB, float scale)
{
    // ---- dispatch-dense decomposition ----
    int tot = 0;
#pragma unroll
    for (int b = 0; b < 16; b++) {
        int a = (cnt[b] + 127) >> 7;
        tot += (EPI == EG_SCORE_C) ? a * a : a * NT;
    }
    const int raw = blockIdx.x;
    if (raw >= tot) return;                      // dispatch tail, uniform exit
    const int q = tot >> 3, r = tot & 7;
    const int xcd = raw & 7, pos = raw >> 3;
    int v = xcd * q + (xcd < r ? xcd : r) + pos; // bijective [0,tot)
    int bz = 0;
    for (;;) {
        int a = (cnt[bz] + 127) >> 7;
        int t = (EPI == EG_SCORE_C) ? a * a : a * NT;
        if (v < t) break;
        v -= t; ++bz;
    }
    int mi, ni;
    if constexpr (EPI == EG_SCORE_C) {
        int a = (cnt[bz] + 127) >> 7;
        mi = v / a; ni = v - mi * a;
    } else {
        mi = v / NT; ni = v - mi * NT;
    }
    const int cb = cnt[bz];
    const int m0 = mi << 7;
    const int n0 = ni << 7;
    const int Kend = (EPI == EG_PV) ? ((cb + 63) & ~63) : K;
    const int nk = Kend >> 6;  // 64-wide K-tiles, >= 1

    constexpr int MI = 2, NI = 4;       // per-wave 32x64 of the 128x128 tile
    constexpr int TSZ = 128 * 64;       // elements per tile buffer (16 KB)

    __shared__ __align__(16) bf16_t Asl[2 * TSZ];
    __shared__ __align__(16) bf16_t Bsl[2 * TSZ];

    const int tid = threadIdx.x;
    const int wid = tid >> 6;     // 0..7
    const int lane = tid & 63;
    const int wm = wid & 3, wn = wid >> 2;

    const bf16_t* Ab = A + (long)bz * sA;
    const bf16_t* Bp = B + (long)bz * sB;

    // staging: per glds, 64 lanes cover 8 rows x 8 chunks(16B); wave wid
    // stages rows wid*16 + q*8 + (lane>>3), q=0,1, for A and B.
    // GLOBAL column chunk pre-XOR'ed with (lane>>3) = row&7 (rule 21).
    const int srow8 = lane >> 3;
    const int scg = ((lane & 7) ^ srow8) << 3;   // element offset in 64-col window

    const bf16_t* pa[2];
    const bf16_t* pb[2];
#pragma unroll
    for (int qq = 0; qq < 2; qq++) {
        pa[qq] = Ab + (long)(m0 + (wid << 4) + (qq << 3) + srow8) * lda + scg;
        pb[qq] = Bp + (long)(n0 + (wid << 4) + (qq << 3) + srow8) * ldb + scg;
    }
    const int wrow = wid << 4;  // wave's first staged row

    // fragment read: row=lane&15; nominal chunk kk*4+(lane>>4) XOR (row&7)
    const int arow = lane & 15;
    const int axr = lane & 7;
    const int f0 = (arow << 6) + (((lane >> 4)      ^ axr) << 3);  // kk=0
    const int f1 = (arow << 6) + ((((lane >> 4) + 4) ^ axr) << 3); // kk=1

    auto stage = [&](int tk, int buf) {
        const long ko = (long)tk << 6;
#pragma unroll
        for (int qq = 0; qq < 2; qq++) {
            async_cp16(pa[qq] + ko, &Asl[buf * TSZ + ((wrow + (qq << 3)) << 6)]);
            async_cp16(pb[qq] + ko, &Bsl[buf * TSZ + ((wrow + (qq << 3)) << 6)]);
        }
    };

    f32x4 acc[MI][NI] = {};

    // prologue
    stage(0, 0);
    __builtin_amdgcn_sched_barrier(0);
    VMW(0); SBAR;

    for (int t = 0; t < nk; ++t) {
        if (t + 1 < nk) stage(t + 1, (t + 1) & 1);

        const int cba = (t & 1) * TSZ;
        bf16x8 af[MI][2], bfr[NI][2];
#pragma unroll
        for (int i = 0; i < MI; i++) {
            const int rb = cba + ((wm * MI + i) << 10);   // (wm*32+i*16)*64
            af[i][0] = *(const bf16x8*)&Asl[rb + f0];
            af[i][1] = *(const bf16x8*)&Asl[rb + f1];
        }
#pragma unroll
        for (int j = 0; j < NI; j++) {
            const int rb = cba + ((wn * NI + j) << 10);   // (wn*64+j*16)*64
            bfr[j][0] = *(const bf16x8*)&Bsl[rb + f0];
            bfr[j][1] = *(const bf16x8*)&Bsl[rb + f1];
        }
        __builtin_amdgcn_sched_barrier(0);
#pragma unroll
        for (int kk = 0; kk < 2; kk++)
#pragma unroll
            for (int i = 0; i < MI; i++)
#pragma unroll
                for (int j = 0; j < NI; j++)
                    acc[i][j] = __builtin_amdgcn_mfma_f32_16x16x32_bf16(
                        af[i][kk], bfr[j][kk], acc[i][j], 0, 0, 0);
        __builtin_amdgcn_sched_barrier(0);
        if (t + 1 < nk) { VMW(0); SBAR; }
    }

    // epilogue — C/D per 16x16 tile: col = lane&15, row = (lane>>4)*4 + reg
    const int mb_ = m0 + wm * 32;
    const int nb_ = n0 + wn * 64;
    const int colw = lane & 15;
    const int rowq = (lane >> 4) << 2;

    if constexpr (EPI == EG_QKV) {
        float bj[NI];
#pragma unroll
        for (int j = 0; j < NI; j++) bj[j] = bias[nb_ + (j << 4) + colw];
        if (nb_ < 1536) {
            bf16_t* C = ((nb_ < 768) ? (bf16_t*)Cout : out2) + (long)bz * 786432;
            const int cbase = (nb_ < 768) ? nb_ : nb_ - 768;
#pragma unroll
            for (int i = 0; i < MI; i++)
#pragma unroll
                for (int j = 0; j < NI; j++)
#pragma unroll
                    for (int r2 = 0; r2 < 4; r2++) {
                        int row = mb_ + (i << 4) + rowq + r2;
                        int col = cbase + (j << 4) + colw;
                        C[(long)row * Hh + col] = (bf16_t)fmaxf(acc[i][j][r2] + bj[j], 0.f);
                    }
        } else {
            bf16_t* C = out3 + (long)bz * 786432;  // vTc[b][h][jc]
#pragma unroll
            for (int i = 0; i < MI; i++) {
                const int jc0 = mb_ + (i << 4) + rowq;
#pragma unroll
                for (int j = 0; j < NI; j++) {
                    const int col = nb_ - 1536 + (j << 4) + colw;
                    bf16x4 o = { (bf16_t)(acc[i][j][0] + bj[j]), (bf16_t)(acc[i][j][1] + bj[j]),
                                 (bf16_t)(acc[i][j][2] + bj[j]), (bf16_t)(acc[i][j][3] + bj[j]) };
                    *(bf16x4*)&C[(long)col * 1024 + jc0] = o;
                }
            }
        }
    } else if constexpr (EPI == EG_SCORE_C) {
        // computed T = k·q^T (rows=keys); store S = T^T, no mask (all tokens valid)
        bf16_t* C = (bf16_t*)Cout + (long)bz * 1048576;
#pragma unroll
        for (int i = 0; i < MI; i++) {
            const int kbase = mb_ + (i << 4) + rowq;
#pragma unroll
            for (int j = 0; j < NI; j++) {
                const int qrow = nb_ + (j << 4) + colw;
                bf16x4 o = { (bf16_t)(acc[i][j][0] * scale), (bf16_t)(acc[i][j][1] * scale),
                             (bf16_t)(acc[i][j][2] * scale), (bf16_t)(acc[i][j][3] * scale) };
                *(bf16x4*)&C[(long)qrow * 1024 + kbase] = o;
            }
        }
    } else if constexpr (EPI == EG_FFN2) {
        float* outp = (float*)Cout;
        const bf16_t* crow = resid + (long)bz * 786432;
        const int* tb = tok + (bz << 10);
        float bj[NI];
#pragma unroll
        for (int j = 0; j < NI; j++) bj[j] = bias[nb_ + (j << 4) + colw];
#pragma unroll
        for (int i = 0; i < MI; i++)
#pragma unroll
            for (int r2 = 0; r2 < 4; r2++) {
                const int jq = mb_ + (i << 4) + rowq + r2;
                if (jq < cb) {
                    const int s = tb[jq];
                    float* orow = outp + ((long)((bz << 10) + s)) * 768;
                    const bf16_t* cr = crow + (long)jq * 768;
#pragma unroll
                    for (int j = 0; j < NI; j++) {
                        const int col = nb_ + (j << 4) + colw;
                        orow[col] = acc[i][j][r2] + bj[j] + (float)cr[col];
                    }
                }
            }
    } else {
        // EG_PV (plain bf16) / EG_FFN1 (relu+bias bf16), compact per-batch
        bf16_t* C = (bf16_t*)Cout + (long)bz * 786432;
        float bj[NI];
#pragma unroll
        for (int j = 0; j < NI; j++) bj[j] = 0.f;
        if constexpr (EPI == EG_FFN1) {
#pragma unroll
            for (int j = 0; j < NI; j++) bj[j] = bias[nb_ + (j << 4) + colw];
        }
#pragma unroll
        for (int i = 0; i < MI; i++)
#pragma unroll
            for (int j = 0; j < NI; j++)
#pragma unroll
                for (int r2 = 0; r2 < 4; r2++) {
                    int row = mb_ + (i << 4) + rowq + r2;
                    int col = nb_ + (j << 4) + colw;
                    float val = acc[i][j][r2] + bj[j];
                    if constexpr (EPI == EG_FFN1) val = fmaxf(val, 0.f);
                    C[(long)row * Hh + col] = (bf16_t)val;
                }
    }
}

// ---- z=0: softmax over compact keys (validity = col < cnt, no mask loads)
// ---- z=1: fill masked output rows with cvec (disjoint from FFN2's rows)
__global__ __launch_bounds__(256) void softmax_rows(
    bf16_t* __restrict__ S_, const int* __restrict__ cnt,
    const int* __restrict__ mask, const float* __restrict__ cvec,
    float* __restrict__ out)
{
    const int b = blockIdx.y;
    const int t = threadIdx.x;

    if (blockIdx.z == 1) {
        const int s = blockIdx.x;
        if (t >= 192 || mask[(b << 10) + s]) return;
        float4 v = ((const float4*)cvec)[t];
        ((float4*)(out + ((long)((b << 10) + s)) * 768))[t] = v;
        return;
    }

    const int jq = blockIdx.x;
    const int cb = cnt[b];
    if (jq >= cb) return;
    bf16_t* p = S_ + (((long)(b << 10)) + jq) * 1024;
    const int t0 = t << 2;

    bf16x4 v4 = *(const bf16x4*)&p[t0];
    float v0 = (t0 + 0 < cb) ? (float)v4[0] : -1e30f;
    float v1 = (t0 + 1 < cb) ? (float)v4[1] : -1e30f;
    float v2 = (t0 + 2 < cb) ? (float)v4[2] : -1e30f;
    float v3 = (t0 + 3 < cb) ? (float)v4[3] : -1e30f;

    float mx = fmaxf(fmaxf(v0, v1), fmaxf(v2, v3));
#pragma unroll
    for (int off = 32; off; off >>= 1) mx = fmaxf(mx, __shfl_down(mx, off, 64));
    __shared__ float redm[4], reds[4];
    if ((t & 63) == 0) redm[t >> 6] = mx;
    __syncthreads();
    mx = fmaxf(fmaxf(redm[0], redm[1]), fmaxf(redm[2], redm[3]));

    // invalid lanes: exp(-1e30 - mx) underflows to exactly 0
    float e0 = __expf(v0 - mx), e1 = __expf(v1 - mx);
    float e2 = __expf(v2 - mx), e3 = __expf(v3 - mx);
    float sm = e0 + e1 + e2 + e3;
#pragma unroll
    for (int off = 32; off; off >>= 1) sm += __shfl_down(sm, off, 64);
    if ((t & 63) == 0) reds[t >> 6] = sm;
    __syncthreads();
    sm = reds[0] + reds[1] + reds[2] + reds[3];

    const float inv = 1.f / sm;
    bf16x4 o = { (bf16_t)(e0 * inv), (bf16_t)(e1 * inv),
                 (bf16_t)(e2 * inv), (bf16_t)(e3 * inv) };
    *(bf16x4*)&p[t0] = o;
}

extern "C" void kernel_launch(void* const* d_in, const int* in_sizes, int n_in,
                              void* d_out, int out_size, void* d_ws, size_t ws_size,
                              hipStream_t stream)
{
    const float* x  = (const float*)d_in[0];
    const int* mask = (const int*)d_in[1];
    const float* Wq = (const float*)d_in[2];
    const float* bq = (const float*)d_in[3];
    const float* Wk = (const float*)d_in[4];
    const float* bk = (const float*)d_in[5];
    const float* Wv = (const float*)d_in[6];
    const float* bv = (const float*)d_in[7];
    const float* W1 = (const float*)d_in[8];
    const float* b1 = (const float*)d_in[9];
    const float* W2 = (const float*)d_in[10];
    const float* b2 = (const float*)d_in[11];
    float* out = (float*)d_out;

    // workspace layout (~140.2 MB)
    char* w = (char*)d_ws;
    bf16_t* xc   = (bf16_t*)(w + 0);            // [16][1024][768] compact, reused as ctxc
    bf16_t* qc   = (bf16_t*)(w + 25165824);     // reused as h1c
    bf16_t* kc   = (bf16_t*)(w + 50331648);
    bf16_t* vTc  = (bf16_t*)(w + 75497472);     // [16][768][1024] compact cols
    bf16_t* sc   = (bf16_t*)(w + 100663296);    // [16][1024][1024] bf16
    bf16_t* wqkv = (bf16_t*)(w + 134217728);    // [2304,768] = Wq|Wk|Wv
    bf16_t* w1b  = (bf16_t*)(w + 137756672);
    bf16_t* w2b  = (bf16_t*)(w + 138936320);
    float*  bqkv = (float*) (w + 140115968);    // [2304]
    int*    tok  = (int*)   (w + 140125184);    // [16][1024]
    int*    cnt  = (int*)   (w + 140190720);    // [16]
    float*  cvec = (float*) (w + 140190784);    // [768]
    bf16_t* ctxc = xc;
    bf16_t* h1c  = qc;

    const float inv_sqrt_h = 0.036084391824351615f; // 1/sqrt(768)
    dim3 blk(256);
    dim3 blk8(512);

    compact_mask<<<16, blk, 0, stream>>>(mask, tok, cnt);
    cvt_all<<<19369, blk, 0, stream>>>(x, Wq, Wk, Wv, W1, W2, bq, bk, bv, b1, b2,
                                       tok, cnt, xc, wqkv, bqkv, cvec);

    // qc|kc|vTc = epi(xc · [Wq|Wk|Wv]^T + bqkv), compact rows; NT=18
    mfma_gemm<EG_QKV, 18><<<2304, blk8, 0, stream>>>(
        xc, wqkv, bqkv, nullptr, tok, cnt, qc, kc, vTc,
        768, 768, 768, 786432, 0, 1.f);

    // sc[jq][jk] = (kc·qc^T)^T * scale  (both dims compact); NT unused
    mfma_gemm<EG_SCORE_C, 1><<<1024, blk8, 0, stream>>>(
        kc, qc, nullptr, nullptr, tok, cnt, sc, nullptr, nullptr,
        768, 768, 768, 786432, 786432, inv_sqrt_h);

    // z=0: softmax over valid keys in place; z=1: masked out rows = cvec
    softmax_rows<<<dim3(1024, 16, 2), blk, 0, stream>>>(sc, cnt, mask, cvec, out);

    // ctxc = sc · vTc^T   (K = ceil64(cnt) per batch); NT=6
    mfma_gemm<EG_PV, 6><<<768, blk8, 0, stream>>>(
        sc, vTc, nullptr, nullptr, tok, cnt, ctxc, nullptr, nullptr,
        0, 1024, 1024, 1048576, 786432, 1.f);

    // h1c = relu(ctxc · W1^T + b1); NT=6
    mfma_gemm<EG_FFN1, 6><<<768, blk8, 0, stream>>>(
        ctxc, w1b, b1, nullptr, tok, cnt, h1c, nullptr, nullptr,
        768, 768, 768, 786432, 0, 1.f);

    // out[b][tok[jq]] = h1c · W2^T + b2 + ctxc   (scatter, fp32); NT=6
    mfma_gemm<EG_FFN2, 6><<<768, blk8, 0, stream>>>(
        h1c, w2b, b2, ctxc, tok, cnt, out, nullptr, nullptr,
        768, 768, 768, 786432, 0, 1.f);
}